// Round 6
// baseline (2606.598 us; speedup 1.0000x reference)
//
#include <hip/hip_runtime.h>

#define MM 8192
#define KK 4096
#define NN 11008
#define BK 32
#define NT (KK / BK)   // 128 K-steps

typedef __attribute__((ext_vector_type(8))) __bf16 bf16x8;
typedef __attribute__((ext_vector_type(4))) float f32x4;
typedef __attribute__((ext_vector_type(4))) int   i32x4;

// Split two f32 into packed bf16 hi parts (RTZ: top 16 bits) and bf16 lo parts
// (bf16 of the exact residual). hi: [bf16(f0) | bf16(f1)] in one u32 via v_perm.
__device__ __forceinline__ uint2 split2(float f0, float f1) {
  unsigned u0 = __float_as_uint(f0), u1 = __float_as_uint(f1);
  unsigned hi = __builtin_amdgcn_perm(u1, u0, 0x07060302u);
  float l0 = f0 - __uint_as_float(u0 & 0xFFFF0000u);   // exact residual
  float l1 = f1 - __uint_as_float(u1 & 0xFFFF0000u);
  unsigned lo = __builtin_amdgcn_perm(__float_as_uint(l1), __float_as_uint(l0), 0x07060302u);
  return make_uint2(hi, lo);
}

// LDS row = 128 B: 8 slots of 16 B. Slot swizzle: slot(row, c) = c ^ f(row&7),
// f(e) = ((e&1)<<2) | (e>>1). f alternates slot-HALVES between adjacent rows,
// so an 8-lane write group (two adjacent rows x 4 k-runs, hi at slot, lo at
// slot^4) covers all 8 slots -> zero write conflicts (round-4 counter decoded:
// old swizzle cost exactly 8 cyc x 32 writes x 128 kt x 5504 blocks = 1.80e8 =
// measured SQ_LDS_BANK_CONFLICT). Reads (8 consecutive lanes = 8 consecutive
// rows, same k-run h) get slots h ^ {f(0..7)} = {0,4,1,5,2,6,3,7} -> all 8
// distinct -> conflict-free. lo plane lives at slot^4 (addr^64).

__global__ __launch_bounds__(256, 2) void dq_gemm_kernel(
    const float* __restrict__ X, const float* __restrict__ W,
    const float* __restrict__ S, float* __restrict__ Y) {
  __shared__ __align__(16) unsigned char sA[128 * 128];  // 16 KiB
  __shared__ __align__(16) unsigned char sB[128 * 128];  // 16 KiB

  const int tid  = (int)threadIdx.x;
  const int lane = tid & 63;
  const int wid  = tid >> 6;

  // ---- grid mapping: XCD-bijective swizzle (5504 = 8*688), then 8-m-tile groups
  int pid = (int)blockIdx.x;
  int sp  = (pid & 7) * 688 + (pid >> 3);
  int grp = sp / 688;
  int rem = sp % 688;
  int tm  = grp * 8 + (rem & 7);             // 0..63
  int tn  = rem >> 3;                        // 0..85
  const int m0 = tm * 128, n0 = tn * 128;

  // ---- staging assignment: thread covers rows {srow, srow+64}, 8 k each
  const int srow = tid >> 2;                 // 0..63
  const int skof = (tid & 3) << 3;           // k offset in floats: 0,8,16,24
  const size_t RSTRIDE = (size_t)64 * KK;
  const float* aptr = X + (size_t)(m0 + srow) * KK + skof;
  const float* bptr = W + (size_t)(n0 + srow) * KK + skof;
  const float* sp0  = S + (size_t)((n0 + srow) >> 6) * 64;
  const float* sp1  = S + (size_t)((n0 + srow + 64) >> 6) * 64;
  const int fw  = ((((srow & 1) << 2) | ((srow & 7) >> 1)) << 4);
  const int wo0 = srow * 128 + (((tid & 3) << 4) ^ fw);
  const int wo1 = wo0 + 64 * 128;            // (srow+64) has same f

  // ---- fragment read offsets (16x16x32: lane holds A[l&15][(l>>4)*8 + j])
  const int wr   = wid >> 1, wc = wid & 1;
  const int frow = lane & 15;
  const int fko  = (lane >> 4) << 4;
  const int fr   = ((((frow & 1) << 2) | ((frow & 7) >> 1)) << 4);
  const int roA  = (wr * 64 + frow) * 128 + (fko ^ fr);
  const int roB  = (wc * 64 + frow) * 128 + (fko ^ fr);

  // two staging register sets for 2-deep prefetch
#define DECL_SET(S) \
  float4 ra0_##S, ra1_##S, ra2_##S, ra3_##S, rb0_##S, rb1_##S, rb2_##S, rb3_##S; \
  float  sc0_##S, sc1_##S;
  DECL_SET(0)
  DECL_SET(1)
  i32x4 hA0, lA0, hA1, lA1, hB0, lB0, hB1, lB1;

#define LOADT(S, kt_) do {                                               \
    const float* pa_ = aptr + (kt_) * BK;                                \
    const float* pb_ = bptr + (kt_) * BK;                                \
    ra0_##S = *(const float4*)(pa_);                                     \
    ra1_##S = *(const float4*)(pa_ + 4);                                 \
    ra2_##S = *(const float4*)(pa_ + RSTRIDE);                           \
    ra3_##S = *(const float4*)(pa_ + RSTRIDE + 4);                       \
    rb0_##S = *(const float4*)(pb_);                                     \
    rb1_##S = *(const float4*)(pb_ + 4);                                 \
    rb2_##S = *(const float4*)(pb_ + RSTRIDE);                           \
    rb3_##S = *(const float4*)(pb_ + RSTRIDE + 4);                       \
    sc0_##S = sp0[(kt_) >> 1];                                           \
    sc1_##S = sp1[(kt_) >> 1];                                           \
  } while (0)

#define CVTT(S) do {                                                          \
    uint2 t_;                                                                 \
    t_ = split2(ra0_##S.x, ra0_##S.y);               hA0.x = t_.x; lA0.x = t_.y; \
    t_ = split2(ra0_##S.z, ra0_##S.w);               hA0.y = t_.x; lA0.y = t_.y; \
    t_ = split2(ra1_##S.x, ra1_##S.y);               hA0.z = t_.x; lA0.z = t_.y; \
    t_ = split2(ra1_##S.z, ra1_##S.w);               hA0.w = t_.x; lA0.w = t_.y; \
    t_ = split2(ra2_##S.x, ra2_##S.y);               hA1.x = t_.x; lA1.x = t_.y; \
    t_ = split2(ra2_##S.z, ra2_##S.w);               hA1.y = t_.x; lA1.y = t_.y; \
    t_ = split2(ra3_##S.x, ra3_##S.y);               hA1.z = t_.x; lA1.z = t_.y; \
    t_ = split2(ra3_##S.z, ra3_##S.w);               hA1.w = t_.x; lA1.w = t_.y; \
    t_ = split2(rb0_##S.x * sc0_##S, rb0_##S.y * sc0_##S); hB0.x = t_.x; lB0.x = t_.y; \
    t_ = split2(rb0_##S.z * sc0_##S, rb0_##S.w * sc0_##S); hB0.y = t_.x; lB0.y = t_.y; \
    t_ = split2(rb1_##S.x * sc0_##S, rb1_##S.y * sc0_##S); hB0.z = t_.x; lB0.z = t_.y; \
    t_ = split2(rb1_##S.z * sc0_##S, rb1_##S.w * sc0_##S); hB0.w = t_.x; lB0.w = t_.y; \
    t_ = split2(rb2_##S.x * sc1_##S, rb2_##S.y * sc1_##S); hB1.x = t_.x; lB1.x = t_.y; \
    t_ = split2(rb2_##S.z * sc1_##S, rb2_##S.w * sc1_##S); hB1.y = t_.x; lB1.y = t_.y; \
    t_ = split2(rb3_##S.x * sc1_##S, rb3_##S.y * sc1_##S); hB1.z = t_.x; lB1.z = t_.y; \
    t_ = split2(rb3_##S.z * sc1_##S, rb3_##S.w * sc1_##S); hB1.w = t_.x; lB1.w = t_.y; \
  } while (0)

#define STORE_LDS() do {                                                 \
    __syncthreads();                       /* readers of prev tile done */ \
    *(i32x4*)&sA[wo0]      = hA0;                                        \
    *(i32x4*)&sA[wo0 ^ 64] = lA0;                                        \
    *(i32x4*)&sA[wo1]      = hA1;                                        \
    *(i32x4*)&sA[wo1 ^ 64] = lA1;                                        \
    *(i32x4*)&sB[wo0]      = hB0;                                        \
    *(i32x4*)&sB[wo0 ^ 64] = lB0;                                        \
    *(i32x4*)&sB[wo1]      = hB1;                                        \
    *(i32x4*)&sB[wo1 ^ 64] = lB1;                                        \
    __syncthreads();                       /* tile visible */            \
  } while (0)

#define COMPUTE() do {                                                   \
    bf16x8 ah[4], al[4], bh[4], bl[4];                                   \
    _Pragma("unroll")                                                    \
    for (int m = 0; m < 4; ++m) {                                        \
      ah[m] = *(const bf16x8*)&sA[roA + m * 2048];                       \
      al[m] = *(const bf16x8*)&sA[(roA + m * 2048) ^ 64];                \
      bh[m] = *(const bf16x8*)&sB[roB + m * 2048];                       \
      bl[m] = *(const bf16x8*)&sB[(roB + m * 2048) ^ 64];                \
    }                                                                    \
    _Pragma("unroll")                                                    \
    for (int m = 0; m < 4; ++m)                                          \
      _Pragma("unroll")                                                  \
      for (int n = 0; n < 4; ++n) {                                      \
        acc[m][n] = __builtin_amdgcn_mfma_f32_16x16x32_bf16(ah[m], bh[n], acc[m][n], 0, 0, 0); \
        acc[m][n] = __builtin_amdgcn_mfma_f32_16x16x32_bf16(al[m], bh[n], acc[m][n], 0, 0, 0); \
        acc[m][n] = __builtin_amdgcn_mfma_f32_16x16x32_bf16(ah[m], bl[n], acc[m][n], 0, 0, 0); \
      }                                                                  \
  } while (0)

  f32x4 acc[4][4];
  const f32x4 z4 = {0.f, 0.f, 0.f, 0.f};
#pragma unroll
  for (int m = 0; m < 4; ++m)
#pragma unroll
    for (int n = 0; n < 4; ++n) acc[m][n] = z4;

  // prologue: 2-deep prefetch
  LOADT(0, 0);
  LOADT(1, 1);
  CVTT(0);                                   // tile 0 ready for first store

  for (int kt = 0; kt < NT; kt += 2) {
    // ---- iter i = kt: loads -> set0, convert tile kt+1 from set1
    if (kt + 2 < NT) LOADT(0, kt + 2);       // issued ~1 full iter before use
    STORE_LDS();                             // tile kt
    COMPUTE();                               // MFMA tile kt
    CVTT(1);                                 // tile kt+1 (loads landed long ago)
    // ---- iter i = kt+1: loads -> set1, convert tile kt+2 from set0
    if (kt + 3 < NT) LOADT(1, kt + 3);
    STORE_LDS();                             // tile kt+1
    COMPUTE();                               // MFMA tile kt+1
    if (kt + 2 < NT) CVTT(0);                // tile kt+2
  }

  // ---- epilogue: C/D layout col=lane&15, row=(lane>>4)*4+reg (m89-verified)
  const size_t orow0 = (size_t)m0 + (size_t)(wr * 64) + (size_t)((lane >> 4) << 2);
  const int    ocol0 = n0 + wc * 64 + frow;
#pragma unroll
  for (int m = 0; m < 4; ++m)
#pragma unroll
    for (int r = 0; r < 4; ++r) {
      float* yp = Y + (orow0 + m * 16 + r) * (size_t)NN + ocol0;
#pragma unroll
      for (int n = 0; n < 4; ++n) yp[n * 16] = acc[m][n][r];
    }
#undef LOADT
#undef CVTT
#undef STORE_LDS
#undef COMPUTE
#undef DECL_SET
}

extern "C" void kernel_launch(void* const* d_in, const int* in_sizes, int n_in,
                              void* d_out, int out_size, void* d_ws, size_t ws_size,
                              hipStream_t stream) {
  const float* X = (const float*)d_in[0];   // (8192, 4096)
  const float* W = (const float*)d_in[1];   // (11008, 4096)
  const float* S = (const float*)d_in[2];   // (172, 64)
  float* Y = (float*)d_out;                 // (8192, 11008)
  const int nwg = (MM / 128) * (NN / 128);  // 64 * 86 = 5504
  dq_gemm_kernel<<<nwg, 256, 0, stream>>>(X, W, S, Y);
}